// Round 3
// baseline (229.928 us; speedup 1.0000x reference)
//
#include <hip/hip_runtime.h>
#include <math.h>

// MoE gate: gate = inp[16384,2048]f32 @ W[64,2048]^T + b[64]; top-2; softmax.
// d_out (float32): [tokens*2] indices-as-floats, then [tokens*2] scores.
//
// Round 5: revert to the two-kernel split-K structure (round-2, 214us) which
// beat the fused 1024-thread block (round-4, 221us; VALUBusy 41.7%, occ 38.8%,
// hbm 10% -> latency-bound, barrier-coupled, zero inter-block stagger).
// Change vs round-2: TM 64->32, block 256->128 threads, grid 1024->2048
// blocks = 8 blocks/CU, 16 waves/CU with 2-wave barriers (was 4 blocks/CU,
// 4-wave barriers). Same 4x4 per-thread blocking, same split-K x4, bitwise-
// identical accumulation order (absmax must stay 0.0).

#define KDIM 2048
#define NEXP 64
#define TM 32
#define BK 32
#define LDSA 36   // 32 tokens + 4 pad (144 B stride, mult of 16 -> b128 ok)
#define LDSW 68   // 64 experts + 4 pad (272 B stride)

__global__ __launch_bounds__(128, 4) void gate_partial_kernel(
    const float* __restrict__ inp,
    const float* __restrict__ W,
    float* __restrict__ partial,   // [S][tokens][NEXP]
    int tokens, int kPerSplit)
{
    __shared__ float As[BK][LDSA];   // As[k][token]
    __shared__ float Ws[BK][LDSW];   // Ws[k][expert]

    const int tid = threadIdx.x;
    const int tx  = tid & 15;        // experts 4*tx..4*tx+3
    const int ty  = tid >> 4;        // tokens 4*ty..4*ty+3 (0..7)
    const int tokBase = blockIdx.x * TM;
    const int split   = blockIdx.y;
    const int k0      = split * kPerSplit;

    // staging map: 128 threads, float4 cols; A: 32 rows x 32 k (2 passes of 16
    // rows), W: 64 rows x 32 k (4 passes of 16 rows)
    const int lrow = tid >> 3;          // 0..15
    const int lcol = (tid & 7) << 2;    // 0,4,...,28

    const float* aPtr0 = inp + (size_t)(tokBase + lrow)      * KDIM + k0 + lcol;
    const float* aPtr1 = inp + (size_t)(tokBase + lrow + 16) * KDIM + k0 + lcol;
    const float* wPtr0 = W   + (size_t)lrow        * KDIM + k0 + lcol;
    const float* wPtr1 = W   + (size_t)(lrow + 16) * KDIM + k0 + lcol;
    const float* wPtr2 = W   + (size_t)(lrow + 32) * KDIM + k0 + lcol;
    const float* wPtr3 = W   + (size_t)(lrow + 48) * KDIM + k0 + lcol;

    float4 aReg0 = *(const float4*)(aPtr0);
    float4 aReg1 = *(const float4*)(aPtr1);
    float4 wReg0 = *(const float4*)(wPtr0);
    float4 wReg1 = *(const float4*)(wPtr1);
    float4 wReg2 = *(const float4*)(wPtr2);
    float4 wReg3 = *(const float4*)(wPtr3);

    float acc[4][4];
    #pragma unroll
    for (int r = 0; r < 4; ++r)
        #pragma unroll
        for (int c = 0; c < 4; ++c) acc[r][c] = 0.0f;

    const int NT = kPerSplit / BK;
    for (int kt = 0; kt < NT; ++kt) {
        __syncthreads();
        #pragma unroll
        for (int c = 0; c < 4; ++c) {
            As[lcol + c][lrow]      = ((const float*)&aReg0)[c];
            As[lcol + c][lrow + 16] = ((const float*)&aReg1)[c];
            Ws[lcol + c][lrow]      = ((const float*)&wReg0)[c];
            Ws[lcol + c][lrow + 16] = ((const float*)&wReg1)[c];
            Ws[lcol + c][lrow + 32] = ((const float*)&wReg2)[c];
            Ws[lcol + c][lrow + 48] = ((const float*)&wReg3)[c];
        }
        __syncthreads();
        if (kt + 1 < NT) {
            const int off = (kt + 1) * BK;
            aReg0 = *(const float4*)(aPtr0 + off);
            aReg1 = *(const float4*)(aPtr1 + off);
            wReg0 = *(const float4*)(wPtr0 + off);
            wReg1 = *(const float4*)(wPtr1 + off);
            wReg2 = *(const float4*)(wPtr2 + off);
            wReg3 = *(const float4*)(wPtr3 + off);
        }
        #pragma unroll 8
        for (int kk = 0; kk < BK; ++kk) {
            const float4 av = *(const float4*)&As[kk][ty << 2];
            const float4 wv = *(const float4*)&Ws[kk][tx << 2];
            const float a[4] = {av.x, av.y, av.z, av.w};
            const float w[4] = {wv.x, wv.y, wv.z, wv.w};
            #pragma unroll
            for (int r = 0; r < 4; ++r)
                #pragma unroll
                for (int c = 0; c < 4; ++c)
                    acc[r][c] = fmaf(a[r], w[c], acc[r][c]);
        }
    }

    // write partials: [split][token][expert], float4 over experts, coalesced in tx
    const int eBase = tx << 2;
    #pragma unroll
    for (int r = 0; r < 4; ++r) {
        const int token = tokBase + (ty << 2) + r;
        float4 v = make_float4(acc[r][0], acc[r][1], acc[r][2], acc[r][3]);
        *(float4*)&partial[((size_t)split * tokens + token) * NEXP + eBase] = v;
    }
}

__global__ __launch_bounds__(256) void reduce_topk_kernel(
    const float* __restrict__ partial,
    const float* __restrict__ bias,
    float* __restrict__ out,
    int tokens, int S)
{
    const int tid = threadIdx.x;
    const int tx  = tid & 15;          // experts 4*tx..4*tx+3
    const int ty  = tid >> 4;          // 16 tokens per block
    const int token = blockIdx.x * 16 + ty;
    const int eBase = tx << 2;

    float4 v = make_float4(0.f, 0.f, 0.f, 0.f);
    for (int s = 0; s < S; ++s) {
        const float4 p = *(const float4*)&partial[((size_t)s * tokens + token) * NEXP + eBase];
        v.x += p.x; v.y += p.y; v.z += p.z; v.w += p.w;
    }
    const float4 bv = *(const float4*)&bias[eBase];
    float g[4] = { v.x + bv.x, v.y + bv.y, v.z + bv.z, v.w + bv.w };

    // local top-2 (ascending scan keeps lower index on ties, matching lax.top_k)
    float v1 = g[0]; int i1 = eBase;
    float v2 = -INFINITY; int i2 = -1;
    #pragma unroll
    for (int c = 1; c < 4; ++c) {
        const float vv = g[c];
        const int   ii = eBase + c;
        if (vv > v1)      { v2 = v1; i2 = i1; v1 = vv; i1 = ii; }
        else if (vv > v2) { v2 = vv; i2 = ii; }
    }
    // 16-lane butterfly merge
    #pragma unroll
    for (int m = 1; m <= 8; m <<= 1) {
        const float ov1 = __shfl_xor(v1, m);
        const int   oi1 = __shfl_xor(i1, m);
        const float ov2 = __shfl_xor(v2, m);
        const int   oi2 = __shfl_xor(i2, m);
        const bool aw = (v1 > ov1) || (v1 == ov1 && i1 < oi1);
        const float nv1 = aw ? v1  : ov1;  const int ni1 = aw ? i1  : oi1;
        const float lv  = aw ? ov1 : v1;   const int li  = aw ? oi1 : i1;
        const float sv  = aw ? v2  : ov2;  const int si  = aw ? i2  : oi2;
        const bool sw = (sv > lv) || (sv == lv && si < li);
        v1 = nv1; i1 = ni1;
        v2 = sw ? sv : lv; i2 = sw ? si : li;
    }
    if (tx == 0) {
        const float e2 = expf(v2 - v1);
        const float denom = 1.0f + e2;
        out[2 * token]     = (float)i1;
        out[2 * token + 1] = (float)i2;
        out[tokens * 2 + 2 * token]     = 1.0f / denom;
        out[tokens * 2 + 2 * token + 1] = e2 / denom;
    }
}

extern "C" void kernel_launch(void* const* d_in, const int* in_sizes, int n_in,
                              void* d_out, int out_size, void* d_ws, size_t ws_size,
                              hipStream_t stream) {
    const float* inp  = (const float*)d_in[0];
    const float* W    = (const float*)d_in[1];
    const float* bias = (const float*)d_in[2];
    float* out = (float*)d_out;
    float* partial = (float*)d_ws;

    const int tokens = in_sizes[0] / KDIM;   // 16384

    // pick largest split S in {4,2,1} whose partial buffer fits d_ws
    int S = 4;
    while (S > 1 && (size_t)S * tokens * NEXP * sizeof(float) > ws_size) S >>= 1;
    const int kPerSplit = KDIM / S;

    dim3 grid(tokens / TM, S);
    gate_partial_kernel<<<grid, 128, 0, stream>>>(inp, W, partial, tokens, kPerSplit);
    reduce_topk_kernel<<<tokens / 16, 256, 0, stream>>>(partial, bias, out, tokens, S);
}